// Round 1
// baseline (168.594 us; speedup 1.0000x reference)
//
#include <hip/hip_runtime.h>
#include <math.h>

// N = 2^22, 22 stages. Each stage: real butterfly + magnitude.
// Stage s (m=2^s) pairs (p, p+m/2); twiddle k = p mod (m/2), angle = 2*pi*k/m.
// out_e = sqrt((e + c*o)^2 + (s*o)^2), out_o = sqrt((e - c*o)^2 + (s*o)^2).
//
// Kernel A: bitrev gather + stages 1..13 inside contiguous 8192-float chunks (LDS).
// Kernel B: stages 14..22 = 9-stage butterfly over 512-elem combs of stride 8192,
//           in-place on d_out (each WG owns a disjoint element set).

#define NBITS 22
#define CHUNK_A 8192        // 2^13
#define LOG_CHUNK_A 13
#define T_SIZE 512          // 2^9 strided elements per comb
#define LOG_T 9
#define STRIDE_B 8192
#define LOW_PER_WG 16
#define TWO_PI 6.28318530717958647692f

__global__ __launch_bounds__(256) void fft_low_stages(const float* __restrict__ x,
                                                      float* __restrict__ y) {
    __shared__ float lds[CHUNK_A];
    const unsigned tid  = threadIdx.x;
    const unsigned base = blockIdx.x * CHUNK_A;

    // Bit-reversed gather load: y[p] = x[rev22(p)]
#pragma unroll
    for (int i = 0; i < CHUNK_A / 256; ++i) {
        unsigned local = i * 256 + tid;
        unsigned p = base + local;
        unsigned src = __brev(p) >> (32 - NBITS);
        lds[local] = x[src];
    }
    __syncthreads();

    // Stages 1..13 in LDS. 4096 pairs, 256 threads -> 16 pairs/thread/stage.
    for (int s = 1; s <= LOG_CHUNK_A; ++s) {
        const unsigned half  = 1u << (s - 1);
        const float inv_m = 1.0f / (float)(1u << s);
#pragma unroll
        for (int i = 0; i < 16; ++i) {
            unsigned q = i * 256 + tid;
            unsigned k = q & (half - 1);
            unsigned e_idx = ((q >> (s - 1)) << s) + k;
            unsigned o_idx = e_idx + half;
            float e = lds[e_idx];
            float o = lds[o_idx];
            float ang = TWO_PI * (float)k * inv_m;
            float sn, c;
            __sincosf(ang, &sn, &c);
            float co = c * o;
            float im = sn * o;
            float re_p = e + co;
            float re_m = e - co;
            float im2 = im * im;
            lds[e_idx] = sqrtf(re_p * re_p + im2);
            lds[o_idx] = sqrtf(re_m * re_m + im2);
        }
        __syncthreads();
    }

    // Contiguous store
#pragma unroll
    for (int i = 0; i < CHUNK_A / 256; ++i) {
        unsigned local = i * 256 + tid;
        y[base + local] = lds[local];
    }
}

// LDS layout [t][li], row stride 17 (16 data + 1 pad) to avoid stride-16 bank conflicts.
__global__ __launch_bounds__(256) void fft_high_stages(float* __restrict__ y) {
    __shared__ float lds[T_SIZE * 17];
    const unsigned tid      = threadIdx.x;
    const unsigned low_base = blockIdx.x * LOW_PER_WG;
    const unsigned li       = tid & 15;     // which low-offset slice
    const unsigned tpart    = tid >> 4;     // 0..15

    // Load: 32 iters x 16 t-values; 64B-granular coalesced (16 consecutive floats per t)
#pragma unroll
    for (int it = 0; it < T_SIZE / 16; ++it) {
        unsigned t = it * 16 + tpart;
        lds[t * 17 + li] = y[low_base + li + (size_t)STRIDE_B * t];
    }
    __syncthreads();

    // Stages 14..22: local stage sig=1..9 over the t dimension.
    // global m = 8192 << sig; k = (low_base+li) + 8192*(q & (half-1))
    for (int sig = 1; sig <= LOG_T; ++sig) {
        const unsigned half = 1u << (sig - 1);
        const float inv_m = 1.0f / (float)(STRIDE_B << sig);
        const float lowf = (float)(low_base + li);
#pragma unroll
        for (int it = 0; it < 16; ++it) {
            unsigned q = it * 16 + tpart;              // pair index within slice, 0..255
            unsigned kq = q & (half - 1);
            unsigned t_e = ((q >> (sig - 1)) << sig) + kq;
            unsigned t_o = t_e + half;
            float e = lds[t_e * 17 + li];
            float o = lds[t_o * 17 + li];
            float kf = lowf + (float)(STRIDE_B * kq);  // exact in fp32 (< 2^22)
            float ang = TWO_PI * kf * inv_m;
            float sn, c;
            __sincosf(ang, &sn, &c);
            float co = c * o;
            float im = sn * o;
            float re_p = e + co;
            float re_m = e - co;
            float im2 = im * im;
            lds[t_e * 17 + li] = sqrtf(re_p * re_p + im2);
            lds[t_o * 17 + li] = sqrtf(re_m * re_m + im2);
        }
        __syncthreads();
    }

    // Store back (same pattern as load)
#pragma unroll
    for (int it = 0; it < T_SIZE / 16; ++it) {
        unsigned t = it * 16 + tpart;
        y[low_base + li + (size_t)STRIDE_B * t] = lds[t * 17 + li];
    }
}

extern "C" void kernel_launch(void* const* d_in, const int* in_sizes, int n_in,
                              void* d_out, int out_size, void* d_ws, size_t ws_size,
                              hipStream_t stream) {
    const float* x = (const float*)d_in[0];
    float* out = (float*)d_out;
    const unsigned N = 1u << NBITS;

    dim3 blkA(256), grdA(N / CHUNK_A);                 // 512 blocks
    fft_low_stages<<<grdA, blkA, 0, stream>>>(x, out);

    dim3 blkB(256), grdB(STRIDE_B / LOW_PER_WG);       // 512 blocks
    fft_high_stages<<<grdB, blkB, 0, stream>>>(out);
}

// Round 2
// 104.330 us; speedup vs baseline: 1.6160x; 1.6160x over previous
//
#include <hip/hip_runtime.h>
#include <math.h>

// N = 2^22, 22 stages of real-butterfly + magnitude (the |.| after every stage
// makes stage order fixed — this is NOT commutable like a real FFT).
// Stage s (m=2^s) pairs (p, p+m/2), twiddle fraction r = (p mod m/2)/m (revolutions):
//   out_e = sqrt((e + c*o)^2 + (s*o)^2), out_o = sqrt((e - c*o)^2 + (s*o)^2).
//
// Kernel A: bitrev gather + stages 1..13 within contiguous 8192-chunks.
//   Radix-8 register groups: stages 1-3 (regs from gather), 4-6, 7-9, 10-12 (LDS
//   round trips), stage 13 fused with coalesced global store.
// Kernel B: stages 14..22 over 512-elem stride-8192 combs, 16 lows per block.
//   Groups 14-16 (regs from global), 17-19 (LDS), 20-22 fused with global store.
//
// v_sin/v_cos take REVOLUTIONS -> pass k/m directly, no 2*pi mult, no range reduce.
// LDS padding A(i)=i+(i>>3) makes every stride-{1,8,64,512,4096} comb <=2-way
// (2-way is free on gfx950).

#define NBITS 22

__device__ __forceinline__ void bf(float& e, float& o, float c, float s) {
    float co = c * o, im = s * o;
    float rp = e + co, rm = e - co;
    float im2 = im * im;
    e = __builtin_amdgcn_sqrtf(fmaf(rp, rp, im2));
    o = __builtin_amdgcn_sqrtf(fmaf(rm, rm, im2));
}

__device__ __forceinline__ void cs(float r, float& c, float& s) {
    c = __builtin_amdgcn_cosf(r);   // cos(2*pi*r)
    s = __builtin_amdgcn_sinf(r);   // sin(2*pi*r); sign irrelevant (squared)
}

// 3 radix-2 stages on 8 register-resident elements.
// Sub-stage i (i=0,1,2) twiddle fraction: b_i + d * 2^-(i+1).
__device__ __forceinline__ void radix8(float v[8], float b0, float b1, float b2) {
    float c, s;
    cs(b0, c, s);
    bf(v[0], v[1], c, s); bf(v[2], v[3], c, s);
    bf(v[4], v[5], c, s); bf(v[6], v[7], c, s);
    cs(b1, c, s);
    bf(v[0], v[2], c, s); bf(v[4], v[6], c, s);
    cs(b1 + 0.25f, c, s);
    bf(v[1], v[3], c, s); bf(v[5], v[7], c, s);
    cs(b2, c, s);           bf(v[0], v[4], c, s);
    cs(b2 + 0.125f, c, s);  bf(v[1], v[5], c, s);
    cs(b2 + 0.25f, c, s);   bf(v[2], v[6], c, s);
    cs(b2 + 0.375f, c, s);  bf(v[3], v[7], c, s);
}

#define PAD(i) ((i) + ((i) >> 3))

__global__ __launch_bounds__(1024, 8) void fft_low(const float* __restrict__ x,
                                                   float* __restrict__ y) {
    __shared__ float lds[9216];               // 8192 + pad
    const unsigned t = threadIdx.x;
    const unsigned base = blockIdx.x * 8192;
    float v[8];

    // bitrev gather: local elements 8t..8t+7
#pragma unroll
    for (int j = 0; j < 8; ++j) {
        unsigned p = base + t * 8 + j;
        v[j] = x[__brev(p) >> (32 - NBITS)];
    }
    // stages 1..3 (h=1, lo=0)
    radix8(v, 0.f, 0.f, 0.f);
#pragma unroll
    for (int j = 0; j < 8; ++j) lds[PAD(t * 8 + j)] = v[j];
    __syncthreads();

    // stages 4..6 (h=8): idx = hi*64 + j*8 + lo
    {
        const unsigned lo = t & 7, hi = t >> 3;
        const unsigned i0 = hi * 64 + lo;
#pragma unroll
        for (int j = 0; j < 8; ++j) v[j] = lds[PAD(i0 + j * 8)];
        const float f = (float)lo;
        radix8(v, f * (1.f/16), f * (1.f/32), f * (1.f/64));
#pragma unroll
        for (int j = 0; j < 8; ++j) lds[PAD(i0 + j * 8)] = v[j];
    }
    __syncthreads();

    // stages 7..9 (h=64): idx = hi*512 + j*64 + lo
    {
        const unsigned lo = t & 63, hi = t >> 6;
        const unsigned i0 = hi * 512 + lo;
#pragma unroll
        for (int j = 0; j < 8; ++j) v[j] = lds[PAD(i0 + j * 64)];
        const float f = (float)lo;
        radix8(v, f * (1.f/128), f * (1.f/256), f * (1.f/512));
#pragma unroll
        for (int j = 0; j < 8; ++j) lds[PAD(i0 + j * 64)] = v[j];
    }
    __syncthreads();

    // stages 10..12 (h=512): idx = hi*4096 + j*512 + lo
    {
        const unsigned lo = t & 511, hi = t >> 9;
        const unsigned i0 = hi * 4096 + lo;
#pragma unroll
        for (int j = 0; j < 8; ++j) v[j] = lds[PAD(i0 + j * 512)];
        const float f = (float)lo;
        radix8(v, f * (1.f/1024), f * (1.f/2048), f * (1.f/4096));
#pragma unroll
        for (int j = 0; j < 8; ++j) lds[PAD(i0 + j * 512)] = v[j];
    }
    __syncthreads();

    // stage 13 (pairs i, i+4096; r = i/8192) fused with coalesced store
#pragma unroll
    for (int it = 0; it < 4; ++it) {
        const unsigned i = it * 1024 + t;
        float e = lds[PAD(i)];
        float o = lds[PAD(i + 4096)];
        float c, s;
        cs((float)i * (1.f/8192), c, s);
        bf(e, o, c, s);
        y[base + i] = e;
        y[base + i + 4096] = o;
    }
}

__global__ __launch_bounds__(1024, 8) void fft_high(float* __restrict__ y) {
    __shared__ float lds[512 * 17 + 16];      // [t][li] row stride 17
    const unsigned tt = threadIdx.x;
    const unsigned li = tt & 15, u = tt >> 4;     // u = 0..63
    const unsigned low = blockIdx.x * 16 + li;
    float v[8];

    // stages 14..16 (t-stride 1): t = 8u + j, straight from global
#pragma unroll
    for (int j = 0; j < 8; ++j) v[j] = y[low + 8192u * (u * 8 + j)];
    {
        const float K = (float)low;
        radix8(v, K * (1.f/16384), K * (1.f/32768), K * (1.f/65536));
    }
#pragma unroll
    for (int j = 0; j < 8; ++j) lds[(u * 8 + j) * 17 + li] = v[j];
    __syncthreads();

    // stages 17..19 (t-stride 8): t = hi*64 + j*8 + lo8
    {
        const unsigned lo8 = u & 7, hi = u >> 3;
        const unsigned t0 = hi * 64 + lo8;
#pragma unroll
        for (int j = 0; j < 8; ++j) v[j] = lds[(t0 + j * 8) * 17 + li];
        const float K = (float)low + 8192.f * (float)lo8;
        radix8(v, K * (1.f/131072), K * (1.f/262144), K * (1.f/524288));
#pragma unroll
        for (int j = 0; j < 8; ++j) lds[(t0 + j * 8) * 17 + li] = v[j];
    }
    __syncthreads();

    // stages 20..22 (t-stride 64): t = j*64 + u, store straight to global
    {
#pragma unroll
        for (int j = 0; j < 8; ++j) v[j] = lds[(u + j * 64) * 17 + li];
        const float K = (float)low + 8192.f * (float)u;
        radix8(v, K * (1.f/1048576), K * (1.f/2097152), K * (1.f/4194304));
#pragma unroll
        for (int j = 0; j < 8; ++j) y[low + 8192u * (u + j * 64)] = v[j];
    }
}

extern "C" void kernel_launch(void* const* d_in, const int* in_sizes, int n_in,
                              void* d_out, int out_size, void* d_ws, size_t ws_size,
                              hipStream_t stream) {
    const float* x = (const float*)d_in[0];
    float* out = (float*)d_out;

    fft_low<<<dim3(512), dim3(1024), 0, stream>>>(x, out);
    fft_high<<<dim3(512), dim3(1024), 0, stream>>>(out);
}

// Round 3
// 101.209 us; speedup vs baseline: 1.6658x; 1.0308x over previous
//
#include <hip/hip_runtime.h>
#include <math.h>

// N = 2^22, 22 stages of real-butterfly + magnitude (|.| after every stage —
// stage order is fixed, NOT commutable like a true FFT).
// Stage s (m=2^s) pairs (p, p+m/2), twiddle fraction r = (p mod m/2)/m (revolutions):
//   out_e = sqrt((e + c*o)^2 + (s*o)^2), out_o = sqrt((e - c*o)^2 + (s*o)^2).
//
// Pipeline (all in/out of d_out, in place after the permute):
//   P: tiled bitrev permute (coalesced both sides via 64x65 LDS tile) + stages 1-3
//   A: stages 4-13 within contiguous 8192-chunks (radix-8 register groups in LDS)
//   B: stages 14-22 over 512-elem stride-8192 combs (16 lows/block, pad-17 rows)
//
// v_sin/v_cos take REVOLUTIONS -> pass k/m directly, no 2*pi mult, no range reduce.

#define NBITS 22

__device__ __forceinline__ void bf(float& e, float& o, float c, float s) {
    float co = c * o, im = s * o;
    float rp = e + co, rm = e - co;
    float im2 = im * im;
    e = __builtin_amdgcn_sqrtf(fmaf(rp, rp, im2));
    o = __builtin_amdgcn_sqrtf(fmaf(rm, rm, im2));
}

__device__ __forceinline__ void cs(float r, float& c, float& s) {
    c = __builtin_amdgcn_cosf(r);   // cos(2*pi*r)
    s = __builtin_amdgcn_sinf(r);   // sin(2*pi*r); sign irrelevant (squared)
}

// 3 radix-2 stages on 8 register-resident elements (v[j] at positions p0+j*h).
// Sub-stage i (i=0,1,2) twiddle fraction: b_i + d * 2^-(i+1), d = index bit pattern.
__device__ __forceinline__ void radix8(float v[8], float b0, float b1, float b2) {
    float c, s;
    cs(b0, c, s);
    bf(v[0], v[1], c, s); bf(v[2], v[3], c, s);
    bf(v[4], v[5], c, s); bf(v[6], v[7], c, s);
    cs(b1, c, s);
    bf(v[0], v[2], c, s); bf(v[4], v[6], c, s);
    cs(b1 + 0.25f, c, s);
    bf(v[1], v[3], c, s); bf(v[5], v[7], c, s);
    cs(b2, c, s);           bf(v[0], v[4], c, s);
    cs(b2 + 0.125f, c, s);  bf(v[1], v[5], c, s);
    cs(b2 + 0.25f, c, s);   bf(v[2], v[6], c, s);
    cs(b2 + 0.375f, c, s);  bf(v[3], v[7], c, s);
}

#define PAD(i) ((i) + ((i) >> 3))

// ---------------- Kernel P: bitrev permute + stages 1..3 ----------------
// p = hi11*2048 + lo11 ; brev22(p) = brev11(lo11)*2048 + brev11(hi11).
// Tile (cb, bb): covers p = brev11(B0+c)*2048 + C0 + tx  for c,tx in [0,64).
// Load rows a = brev11(C0+r) coalesced (256B runs); store 256B runs per c.
__global__ __launch_bounds__(256) void fft_perm(const float* __restrict__ x,
                                                float* __restrict__ y) {
    __shared__ float lds[64 * 65];
    const unsigned tid = threadIdx.x;
    const unsigned tx = tid & 63, g = tid >> 6;        // g = 0..3
    const unsigned C0 = (blockIdx.x & 31) * 64;
    const unsigned B0 = (blockIdx.x >> 5) * 64;

#pragma unroll
    for (int k = 0; k < 16; ++k) {
        unsigned r = g * 16 + k;
        unsigned a = __brev(C0 + r) >> (32 - 11);
        lds[r * 65 + tx] = x[a * 2048u + B0 + tx];
    }
    __syncthreads();

    float v[8];
#pragma unroll
    for (int q = 0; q < 2; ++q) {
        unsigned task = tid + 256u * q;                // 0..511
        unsigned c = task >> 3, grp = task & 7;
        // 8 consecutive p-values: p = pr*2048 + C0 + grp*8 + j (8-aligned run)
#pragma unroll
        for (int j = 0; j < 8; ++j) v[j] = lds[(grp * 8 + j) * 65 + c];
        radix8(v, 0.f, 0.f, 0.f);                      // stages 1..3 (k from j bits)
        unsigned pr = __brev(B0 + c) >> (32 - 11);
        float* dst = y + pr * 2048u + C0 + grp * 8;
        *(float4*)(dst)     = make_float4(v[0], v[1], v[2], v[3]);
        *(float4*)(dst + 4) = make_float4(v[4], v[5], v[6], v[7]);
    }
}

// ---------------- Kernel A: stages 4..13 ----------------
__global__ __launch_bounds__(1024, 4) void fft_low(float* __restrict__ y) {
    __shared__ float lds[9216];               // 8192 + pad
    const unsigned t = threadIdx.x;
    const unsigned base = blockIdx.x * 8192;
    float v[8];

    // contiguous load (post stage-3 data)
    const float4* src = (const float4*)(y + base + t * 8);
    float4 u0 = src[0], u1 = src[1];
    v[0] = u0.x; v[1] = u0.y; v[2] = u0.z; v[3] = u0.w;
    v[4] = u1.x; v[5] = u1.y; v[6] = u1.z; v[7] = u1.w;
#pragma unroll
    for (int j = 0; j < 8; ++j) lds[PAD(t * 8 + j)] = v[j];
    __syncthreads();

    // stages 4..6 (h=8): idx = hi*64 + j*8 + lo
    {
        const unsigned lo = t & 7, hi = t >> 3;
        const unsigned i0 = hi * 64 + lo;
#pragma unroll
        for (int j = 0; j < 8; ++j) v[j] = lds[PAD(i0 + j * 8)];
        const float f = (float)lo;
        radix8(v, f * (1.f/16), f * (1.f/32), f * (1.f/64));
#pragma unroll
        for (int j = 0; j < 8; ++j) lds[PAD(i0 + j * 8)] = v[j];
    }
    __syncthreads();

    // stages 7..9 (h=64): idx = hi*512 + j*64 + lo
    {
        const unsigned lo = t & 63, hi = t >> 6;
        const unsigned i0 = hi * 512 + lo;
#pragma unroll
        for (int j = 0; j < 8; ++j) v[j] = lds[PAD(i0 + j * 64)];
        const float f = (float)lo;
        radix8(v, f * (1.f/128), f * (1.f/256), f * (1.f/512));
#pragma unroll
        for (int j = 0; j < 8; ++j) lds[PAD(i0 + j * 64)] = v[j];
    }
    __syncthreads();

    // stages 10..12 (h=512): idx = hi*4096 + j*512 + lo
    {
        const unsigned lo = t & 511, hi = t >> 9;
        const unsigned i0 = hi * 4096 + lo;
#pragma unroll
        for (int j = 0; j < 8; ++j) v[j] = lds[PAD(i0 + j * 512)];
        const float f = (float)lo;
        radix8(v, f * (1.f/1024), f * (1.f/2048), f * (1.f/4096));
#pragma unroll
        for (int j = 0; j < 8; ++j) lds[PAD(i0 + j * 512)] = v[j];
    }
    __syncthreads();

    // stage 13 (pairs i, i+4096; r = i/8192) fused with coalesced store
#pragma unroll
    for (int it = 0; it < 4; ++it) {
        const unsigned i = it * 1024 + t;
        float e = lds[PAD(i)];
        float o = lds[PAD(i + 4096)];
        float c, s;
        cs((float)i * (1.f/8192), c, s);
        bf(e, o, c, s);
        y[base + i] = e;
        y[base + i + 4096] = o;
    }
}

// ---------------- Kernel B: stages 14..22 ----------------
__global__ __launch_bounds__(1024, 4) void fft_high(float* __restrict__ y) {
    __shared__ float lds[512 * 17 + 16];      // [t][li] row stride 17
    const unsigned tt = threadIdx.x;
    const unsigned li = tt & 15, u = tt >> 4;     // u = 0..63
    const unsigned low = blockIdx.x * 16 + li;
    float v[8];

    // stages 14..16 (t-stride 1): t = 8u + j, straight from global
#pragma unroll
    for (int j = 0; j < 8; ++j) v[j] = y[low + 8192u * (u * 8 + j)];
    {
        const float K = (float)low;
        radix8(v, K * (1.f/16384), K * (1.f/32768), K * (1.f/65536));
    }
#pragma unroll
    for (int j = 0; j < 8; ++j) lds[(u * 8 + j) * 17 + li] = v[j];
    __syncthreads();

    // stages 17..19 (t-stride 8): t = hi*64 + j*8 + lo8
    {
        const unsigned lo8 = u & 7, hi = u >> 3;
        const unsigned t0 = hi * 64 + lo8;
#pragma unroll
        for (int j = 0; j < 8; ++j) v[j] = lds[(t0 + j * 8) * 17 + li];
        const float K = (float)low + 8192.f * (float)lo8;
        radix8(v, K * (1.f/131072), K * (1.f/262144), K * (1.f/524288));
#pragma unroll
        for (int j = 0; j < 8; ++j) lds[(t0 + j * 8) * 17 + li] = v[j];
    }
    __syncthreads();

    // stages 20..22 (t-stride 64): t = j*64 + u, store straight to global
    {
#pragma unroll
        for (int j = 0; j < 8; ++j) v[j] = lds[(u + j * 64) * 17 + li];
        const float K = (float)low + 8192.f * (float)u;
        radix8(v, K * (1.f/1048576), K * (1.f/2097152), K * (1.f/4194304));
#pragma unroll
        for (int j = 0; j < 8; ++j) y[low + 8192u * (u + j * 64)] = v[j];
    }
}

extern "C" void kernel_launch(void* const* d_in, const int* in_sizes, int n_in,
                              void* d_out, int out_size, void* d_ws, size_t ws_size,
                              hipStream_t stream) {
    const float* x = (const float*)d_in[0];
    float* out = (float*)d_out;

    fft_perm<<<dim3(1024), dim3(256), 0, stream>>>(x, out);
    fft_low<<<dim3(512), dim3(1024), 0, stream>>>(out);
    fft_high<<<dim3(512), dim3(1024), 0, stream>>>(out);
}